// Round 12
// baseline (796.400 us; speedup 1.0000x reference)
//
#include <hip/hip_runtime.h>

typedef __bf16 bf16;
typedef __bf16 bf16x4 __attribute__((ext_vector_type(4)));
typedef __bf16 bf16x8 __attribute__((ext_vector_type(8)));
typedef float f32x4 __attribute__((ext_vector_type(4)));

#define SCLOG 0.1803368801111244f   // 0.125 * log2(e)

constexpr int Bsz = 8, N = 2048, IN = 256, H = 8, D = 64;
constexpr int M = Bsz * N;       // 16384 rows
constexpr int HD = H * D;        // 512
constexpr int QKV = 3 * HD;      // 1536

// Stage 8 rows x 64 cols (bf16) into LDS via global_load_lds, 16B/lane.
// LDS dest linear; source column pre-swizzled (XOR r8) so swizzled ds_reads
// land conflict-free (both-sides rule).
__device__ __forceinline__ void stage8(const bf16* __restrict__ src, size_t stride,
                                       bf16* ldsBase, int row0, int lane) {
    int r8 = lane >> 3;
    int cb = ((lane & 7) ^ r8) << 4;
    const bf16* g = src + (size_t)(row0 + r8) * stride + (cb >> 1);
    bf16* l = ldsBase + row0 * 64;
    __builtin_amdgcn_global_load_lds(
        (const __attribute__((address_space(1))) char*)g,
        (__attribute__((address_space(3))) char*)l, 16, 0, 0);
}

// ---------------- prep kernels ----------------
__global__ void cvt_msg(const float* __restrict__ in, bf16* __restrict__ out) {
    int i = blockIdx.x * blockDim.x + threadIdx.x;   // one float4 per thread
    float4 v = ((const float4*)in)[i];
    bf16x4 o = { (bf16)v.x, (bf16)v.y, (bf16)v.z, (bf16)v.w };
    ((bf16x4*)out)[i] = o;
}

// Tiled transposes: Wq/Wk/Wv (256x512) -> Wt rows, Wo (512x64) -> Wot, + bias.
__global__ __launch_bounds__(256) void pack_w(
    const float* __restrict__ Wq, const float* __restrict__ Wk,
    const float* __restrict__ Wv, const float* __restrict__ bq,
    const float* __restrict__ bk, const float* __restrict__ bv,
    const float* __restrict__ Wo,
    bf16* __restrict__ Wt, float* __restrict__ bias, bf16* __restrict__ Wot) {
    __shared__ float Tt[32][33];
    const int tid = blockIdx.x;
    const int tx = threadIdx.x & 31, ty = threadIdx.x >> 5;   // 32 x 8
    if (tid < 384) {                       // 128 tiles per W (8 k-tiles x 16 c-tiles)
        int wsel = tid >> 7, t = tid & 127;
        int k0 = (t >> 4) * 32, cl0 = (t & 15) * 32;
        const float* W = wsel == 0 ? Wq : (wsel == 1 ? Wk : Wv);
#pragma unroll
        for (int i = 0; i < 4; ++i)
            Tt[ty + i * 8][tx] = W[(size_t)(k0 + ty + i * 8) * HD + cl0 + tx];
        __syncthreads();
#pragma unroll
        for (int i = 0; i < 4; ++i)
            Wt[(size_t)(wsel * HD + cl0 + ty + i * 8) * IN + k0 + tx] =
                (bf16)Tt[tx][ty + i * 8];
    } else if (tid < 416) {                // Wo 512x64: 16 x 2 tiles
        int t = tid - 384;
        int r0 = (t >> 1) * 32, c0 = (t & 1) * 32;
#pragma unroll
        for (int i = 0; i < 4; ++i)
            Tt[ty + i * 8][tx] = Wo[(size_t)(r0 + ty + i * 8) * D + c0 + tx];
        __syncthreads();
#pragma unroll
        for (int i = 0; i < 4; ++i)
            Wot[(size_t)(c0 + ty + i * 8) * HD + r0 + tx] = (bf16)Tt[tx][ty + i * 8];
    } else {                               // bias concat
        for (int v = threadIdx.x; v < QKV; v += 256)
            bias[v] = v < HD ? bq[v] : (v < 2 * HD ? bk[v - HD] : bv[v - 2 * HD]);
    }
}

// ---------------- QKV projection GEMM (LDS-staged, double-buffered) --------
__global__ __launch_bounds__(256) void qkv_gemm(
    const bf16* __restrict__ A, const bf16* __restrict__ Wt,
    const float* __restrict__ bias,
    bf16* __restrict__ Q, bf16* __restrict__ K, bf16* __restrict__ Vt) {
    __shared__ __align__(16) char smem[65536];  // [2][As 16K|Bs 16K]; epilogue Tv alias
    const int w = threadIdx.x >> 6, lane = threadIdx.x & 63;
    const int lr = lane & 15, lg = lane >> 4;
    const int mblk = blockIdx.x * 128;
    const int m0 = mblk + w * 32;
    const int c0 = blockIdx.y * 128;
    const int swz = (lr & 7) << 4;

    auto stage_step = [&](int buf, int kk) {
        bf16* as_ = (bf16*)(smem + buf * 32768);
        bf16* bs_ = (bf16*)(smem + buf * 32768 + 16384);
#pragma unroll
        for (int j = 0; j < 4; ++j) {
            stage8(A + (size_t)mblk * IN + kk, IN, as_, w * 32 + j * 8, lane);
            stage8(Wt + (size_t)c0 * IN + kk, IN, bs_, w * 32 + j * 8, lane);
        }
    };

    f32x4 acc[2][8] = {};
    stage_step(0, 0);
    __syncthreads();
    int cur = 0;

    for (int kstep = 0; kstep < 4; ++kstep) {
        if (kstep < 3) stage_step(cur ^ 1, (kstep + 1) * 64);
        const char* abase = smem + cur * 32768;
        const char* bbase = abase + 16384;
        const char* arow = abase + (w * 32) * 128;
#pragma unroll
        for (int ks = 0; ks < 2; ++ks) {
            bf16x8 a0 = *(const bf16x8*)(arow + lr * 128 + ((ks * 64 + lg * 16) ^ swz));
            bf16x8 a1 = *(const bf16x8*)(arow + (16 + lr) * 128 + ((ks * 64 + lg * 16) ^ swz));
#pragma unroll
            for (int nt = 0; nt < 8; ++nt) {
                bf16x8 bf = *(const bf16x8*)(bbase + (nt * 16 + lr) * 128 + ((ks * 64 + lg * 16) ^ swz));
                acc[0][nt] = __builtin_amdgcn_mfma_f32_16x16x32_bf16(a0, bf, acc[0][nt], 0, 0, 0);
                acc[1][nt] = __builtin_amdgcn_mfma_f32_16x16x32_bf16(a1, bf, acc[1][nt], 0, 0, 0);
            }
        }
        __syncthreads();
        cur ^= 1;
    }

    if (c0 < 2 * HD) {
        bf16* dst = (c0 < HD) ? Q : K;
#pragma unroll
        for (int mt = 0; mt < 2; ++mt) {
            int rowb = m0 + mt * 16 + lg * 4;
#pragma unroll
            for (int nt = 0; nt < 8; ++nt) {
                int cc = (c0 + nt * 16 + lr) & (HD - 1);
                float bv = bias[c0 + nt * 16 + lr];
                int h = cc >> 6, d = cc & 63;
#pragma unroll
                for (int r = 0; r < 4; ++r) {
                    int row = rowb + r;
                    int b = row >> 11, n = row & (N - 1);
                    dst[(((size_t)(b * H + h) * N) + n) * D + d] =
                        (bf16)(acc[mt][nt][r] + bv);
                }
            }
        }
    } else {
        bf16 (*Tv)[136] = (bf16(*)[136])smem;   // 272B stride: b64/b128 aligned
#pragma unroll
        for (int mt = 0; mt < 2; ++mt) {
            int mb = w * 32 + mt * 16 + lg * 4;
#pragma unroll
            for (int nt = 0; nt < 8; ++nt) {
                int cl = nt * 16 + lr;
                float bv = bias[c0 + cl];
                bf16x4 pk = { (bf16)(acc[mt][nt][0] + bv), (bf16)(acc[mt][nt][1] + bv),
                              (bf16)(acc[mt][nt][2] + bv), (bf16)(acc[mt][nt][3] + bv) };
                *(bf16x4*)&Tv[cl][mb] = pk;
            }
        }
        __syncthreads();
        const int cc0 = c0 - 2 * HD;
        const int b = mblk >> 11;
        const int nb = mblk & (N - 1);
        const int j = threadIdx.x & 15;
#pragma unroll
        for (int pass = 0; pass < 8; ++pass) {
            int cl = pass * 16 + (threadIdx.x >> 4);
            int cc = cc0 + cl, h = cc >> 6, d = cc & 63;
            bf16x8 vv = *(const bf16x8*)&Tv[cl][j * 8];
            *(bf16x8*)(Vt + ((size_t)(b * H + h) * D + d) * N + nb + j * 8) = vv;
        }
    }
}

// ---------------- fused attention v5 ----------------
// v4 + per-qt P roundtrip: P LDS halved to [8][16][64] (16 KB), qt=1 reuses
// qt=0's rows (DS ops in-order per wave -> no sync). Total LDS 48 KB ->
// 3 blocks/CU = 24 waves/CU (was 2/16). launch_bounds(512,6) caps VGPR at 85.
__global__ __launch_bounds__(512, 6) void attn_kernel(
    const bf16* __restrict__ Qg, const bf16* __restrict__ Kg,
    const bf16* __restrict__ Vtg, bf16* __restrict__ ctx) {
    __shared__ bf16 Kb[2][64][64];   // 16 KB
    __shared__ bf16 Vb[2][64][64];   // 16 KB  (rows d, cols k)
    __shared__ bf16 P[8][16][64];    // 16 KB, XOR-swizzled rows (128B)
    const int w = threadIdx.x >> 6, lane = threadIdx.x & 63;
    const int lr = lane & 15, lg = lane >> 4;
    const int bh = blockIdx.x;
    const int q0 = blockIdx.y * 256 + w * 32;   // wave's 32 q-rows

    const bf16* Qp = Qg + (size_t)bh * N * D;
    const bf16* Kp = Kg + (size_t)bh * N * D;
    const bf16* Vp = Vtg + (size_t)bh * D * N;

    bf16x8 qf[2][2];
#pragma unroll
    for (int qt = 0; qt < 2; ++qt)
#pragma unroll
        for (int kd = 0; kd < 2; ++kd)
            qf[qt][kd] = *(const bf16x8*)(Qp + (size_t)(q0 + qt * 16 + lr) * D + kd * 32 + lg * 8);

    const bf16 onev = (bf16)1.0f;
    const bf16x8 ones = { onev, onev, onev, onev, onev, onev, onev, onev };

    float mrow[2] = { -1e30f, -1e30f };   // running max (lane layout q = lr+16qt)
    float lrow[2][4] = {};                // denom  (cacc layout q = 4*lg+r)
    f32x4 cacc[2][4] = {};                // rows q = 4*lg + r, cols d = dt*16 + lr

    stage8(Kp, 64, &Kb[0][0][0], w * 8, lane);
    stage8(Vp, N,  &Vb[0][0][0], w * 8, lane);
    __syncthreads();
    int cur = 0;

    const int swz = (lr & 7) << 4;
    char* prow0 = (char*)&P[w][lr][0];

    for (int kt = 0; kt < N / 64; ++kt) {
        const int kk0 = kt * 64;
        if (kt + 1 < N / 64) {
            stage8(Kp + (size_t)(kk0 + 64) * 64, 64, &Kb[cur ^ 1][0][0], w * 8, lane);
            stage8(Vp + (kk0 + 64),         N,  &Vb[cur ^ 1][0][0], w * 8, lane);
        }
        const char* kbase = (const char*)&Kb[cur][0][0];
        f32x4 s[2][4] = {};
#pragma unroll
        for (int nt = 0; nt < 4; ++nt)
#pragma unroll
            for (int kd = 0; kd < 2; ++kd) {
                bf16x8 kf = *(const bf16x8*)(kbase + (nt * 16 + lr) * 128 + ((kd * 64 + lg * 16) ^ swz));
                s[0][nt] = __builtin_amdgcn_mfma_f32_16x16x32_bf16(kf, qf[0][kd], s[0][nt], 0, 0, 0);
                s[1][nt] = __builtin_amdgcn_mfma_f32_16x16x32_bf16(kf, qf[1][kd], s[1][nt], 0, 0, 0);
            }
        if (kk0 < q0 + 32 && q0 < kk0 + 64) {
#pragma unroll
            for (int qt = 0; qt < 2; ++qt) {
                int q = q0 + qt * 16 + lr;
#pragma unroll
                for (int nt = 0; nt < 4; ++nt)
#pragma unroll
                    for (int r = 0; r < 4; ++r)
                        if (kk0 + nt * 16 + lg * 4 + r == q) s[qt][nt][r] = -3e38f;
            }
        }
        float rm[2];
        bool need = false;
#pragma unroll
        for (int qt = 0; qt < 2; ++qt) {
            float v = s[qt][0][0];
#pragma unroll
            for (int nt = 0; nt < 4; ++nt)
#pragma unroll
                for (int r = 0; r < 4; ++r) v = fmaxf(v, s[qt][nt][r]);
            v = fmaxf(v, __shfl_xor(v, 16));
            v = fmaxf(v, __shfl_xor(v, 32));
            rm[qt] = v;
            need = need || (v > mrow[qt] + 64.f);
        }
        if (__any(need)) {
#pragma unroll
            for (int qt = 0; qt < 2; ++qt) {
                float mn = fmaxf(mrow[qt], rm[qt]);
                float f = exp2f((mrow[qt] - mn) * SCLOG);
                mrow[qt] = mn;
#pragma unroll
                for (int r = 0; r < 4; ++r) {
                    float fr = __shfl(f, lg * 4 + r);
                    lrow[qt][r] *= fr;
#pragma unroll
                    for (int dt = 0; dt < 4; ++dt) cacc[qt][dt][r] *= fr;
                }
            }
        }
        // ---- per-qt: P -> LDS (16 rows, shared across qt) -> PV MFMAs
        const char* vbase = (const char*)&Vb[cur][0][0];
#pragma unroll
        for (int qt = 0; qt < 2; ++qt) {
            float mc = mrow[qt] * SCLOG;
#pragma unroll
            for (int nt = 0; nt < 4; ++nt) {
                float p0 = exp2f(__builtin_fmaf(s[qt][nt][0], SCLOG, -mc));
                float p1 = exp2f(__builtin_fmaf(s[qt][nt][1], SCLOG, -mc));
                float p2 = exp2f(__builtin_fmaf(s[qt][nt][2], SCLOG, -mc));
                float p3 = exp2f(__builtin_fmaf(s[qt][nt][3], SCLOG, -mc));
                bf16x4 pk = { (bf16)p0, (bf16)p1, (bf16)p2, (bf16)p3 };
                *(bf16x4*)(prow0 + ((nt * 32 + lg * 8) ^ swz)) = pk;
            }
            bf16x8 pa[2];
            f32x4 sacc = {};
#pragma unroll
            for (int ks = 0; ks < 2; ++ks) {
                pa[ks] = *(const bf16x8*)(prow0 + ((ks * 64 + lg * 16) ^ swz));
                sacc = __builtin_amdgcn_mfma_f32_16x16x32_bf16(pa[ks], ones, sacc, 0, 0, 0);
            }
#pragma unroll
            for (int ks = 0; ks < 2; ++ks)
#pragma unroll
                for (int dt = 0; dt < 4; ++dt) {
                    bf16x8 vf = *(const bf16x8*)(vbase + (dt * 16 + lr) * 128 + ((ks * 64 + lg * 16) ^ swz));
                    cacc[qt][dt] = __builtin_amdgcn_mfma_f32_16x16x32_bf16(pa[ks], vf, cacc[qt][dt], 0, 0, 0);
                }
#pragma unroll
            for (int r = 0; r < 4; ++r) lrow[qt][r] += sacc[r];
        }
        __syncthreads();
        cur ^= 1;
    }
    const int b = bh >> 3, h = bh & 7;
#pragma unroll
    for (int qt = 0; qt < 2; ++qt) {
#pragma unroll
        for (int r = 0; r < 4; ++r) {
            float oolr = 1.0f / lrow[qt][r];
            int q = q0 + qt * 16 + lg * 4 + r;
#pragma unroll
            for (int dt = 0; dt < 4; ++dt)
                ctx[((size_t)(b * N + q)) * HD + h * 64 + dt * 16 + lr] =
                    (bf16)(cacc[qt][dt][r] * oolr);
        }
    }
}

// ---------------- output projection ----------------
__global__ __launch_bounds__(256) void out_gemm(
    const bf16* __restrict__ ctx, const bf16* __restrict__ Wot,
    float* __restrict__ out) {
    const int w = threadIdx.x >> 6, lane = threadIdx.x & 63;
    const int lr = lane & 15, lg = lane >> 4;
    const int m0 = blockIdx.x * 64 + w * 16;
    f32x4 acc[4] = {};
#pragma unroll
    for (int ks = 0; ks < 16; ++ks) {
        bf16x8 af = *(const bf16x8*)(ctx + (size_t)(m0 + lr) * HD + ks * 32 + lg * 8);
#pragma unroll
        for (int nt = 0; nt < 4; ++nt) {
            bf16x8 wf = *(const bf16x8*)(Wot + (size_t)(nt * 16 + lr) * HD + ks * 32 + lg * 8);
            acc[nt] = __builtin_amdgcn_mfma_f32_16x16x32_bf16(af, wf, acc[nt], 0, 0, 0);
        }
    }
#pragma unroll
    for (int nt = 0; nt < 4; ++nt)
#pragma unroll
        for (int r = 0; r < 4; ++r)
            out[(size_t)(m0 + lg * 4 + r) * D + nt * 16 + lr] = acc[nt][r];
}

// ---------------- launcher ----------------
extern "C" void kernel_launch(void* const* d_in, const int* in_sizes, int n_in,
                              void* d_out, int out_size, void* d_ws, size_t ws_size,
                              hipStream_t stream) {
    (void)in_sizes; (void)n_in; (void)out_size; (void)ws_size;
    const float* msg = (const float*)d_in[0];
    const float* Wq  = (const float*)d_in[1];
    const float* bq  = (const float*)d_in[2];
    const float* Wk  = (const float*)d_in[3];
    const float* bk  = (const float*)d_in[4];
    const float* Wv  = (const float*)d_in[5];
    const float* bv  = (const float*)d_in[6];
    const float* Wo  = (const float*)d_in[7];
    float* out = (float*)d_out;

    char* p = (char*)d_ws;
    bf16*  Abf  = (bf16*)p;  p += (size_t)M * IN * 2;      // 8 MB
    bf16*  Wt   = (bf16*)p;  p += (size_t)QKV * IN * 2;    // 768 KB
    float* bias = (float*)p; p += (size_t)QKV * 4;         // 6 KB
    bf16*  Wot  = (bf16*)p;  p += (size_t)D * HD * 2;      // 64 KB
    bf16*  Qb   = (bf16*)p;  p += (size_t)Bsz * H * N * D * 2;   // 16 MB
    bf16*  Kb   = (bf16*)p;  p += (size_t)Bsz * H * N * D * 2;   // 16 MB
    bf16*  Vtb  = (bf16*)p;  p += (size_t)Bsz * H * D * N * 2;   // 16 MB
    bf16*  Ctx  = (bf16*)p;  p += (size_t)M * HD * 2;            // 16 MB

    cvt_msg<<<(M * IN / 4) / 256, 256, 0, stream>>>(msg, Abf);
    pack_w<<<417, 256, 0, stream>>>(Wq, Wk, Wv, bq, bk, bv, Wo, Wt, bias, Wot);

    dim3 g1(M / 128, QKV / 128);     // 128 x 12
    qkv_gemm<<<g1, 256, 0, stream>>>(Abf, Wt, bias, Qb, Kb, Vtb);

    dim3 g2(Bsz * H, N / 256);       // 64 x 8 : 512 blocks, 3/CU
    attn_kernel<<<g2, 512, 0, stream>>>(Qb, Kb, Vtb, Ctx);

    out_gemm<<<M / 64, 256, 0, stream>>>(Ctx, Wot, out);
}

// Round 13
// 263.670 us; speedup vs baseline: 3.0204x; 3.0204x over previous
//
#include <hip/hip_runtime.h>

typedef __bf16 bf16;
typedef __bf16 bf16x4 __attribute__((ext_vector_type(4)));
typedef __bf16 bf16x8 __attribute__((ext_vector_type(8)));
typedef float f32x4 __attribute__((ext_vector_type(4)));

#define SCLOG 0.1803368801111244f   // 0.125 * log2(e)

constexpr int Bsz = 8, N = 2048, IN = 256, H = 8, D = 64;
constexpr int M = Bsz * N;       // 16384 rows
constexpr int HD = H * D;        // 512
constexpr int QKV = 3 * HD;      // 1536

// Stage 8 rows x 64 cols (bf16) into LDS via global_load_lds, 16B/lane.
// LDS dest linear; source column pre-swizzled (XOR r8) so swizzled ds_reads
// land conflict-free (both-sides rule).
__device__ __forceinline__ void stage8(const bf16* __restrict__ src, size_t stride,
                                       bf16* ldsBase, int row0, int lane) {
    int r8 = lane >> 3;
    int cb = ((lane & 7) ^ r8) << 4;
    const bf16* g = src + (size_t)(row0 + r8) * stride + (cb >> 1);
    bf16* l = ldsBase + row0 * 64;
    __builtin_amdgcn_global_load_lds(
        (const __attribute__((address_space(1))) char*)g,
        (__attribute__((address_space(3))) char*)l, 16, 0, 0);
}

// ---------------- prep kernels ----------------
__global__ void cvt_msg(const float* __restrict__ in, bf16* __restrict__ out) {
    int i = blockIdx.x * blockDim.x + threadIdx.x;   // one float4 per thread
    float4 v = ((const float4*)in)[i];
    bf16x4 o = { (bf16)v.x, (bf16)v.y, (bf16)v.z, (bf16)v.w };
    ((bf16x4*)out)[i] = o;
}

// Tiled transposes: Wq/Wk/Wv (256x512) -> Wt rows, Wo (512x64) -> Wot, + bias.
__global__ __launch_bounds__(256) void pack_w(
    const float* __restrict__ Wq, const float* __restrict__ Wk,
    const float* __restrict__ Wv, const float* __restrict__ bq,
    const float* __restrict__ bk, const float* __restrict__ bv,
    const float* __restrict__ Wo,
    bf16* __restrict__ Wt, float* __restrict__ bias, bf16* __restrict__ Wot) {
    __shared__ float Tt[32][33];
    const int tid = blockIdx.x;
    const int tx = threadIdx.x & 31, ty = threadIdx.x >> 5;   // 32 x 8
    if (tid < 384) {                       // 128 tiles per W (8 k-tiles x 16 c-tiles)
        int wsel = tid >> 7, t = tid & 127;
        int k0 = (t >> 4) * 32, cl0 = (t & 15) * 32;
        const float* W = wsel == 0 ? Wq : (wsel == 1 ? Wk : Wv);
#pragma unroll
        for (int i = 0; i < 4; ++i)
            Tt[ty + i * 8][tx] = W[(size_t)(k0 + ty + i * 8) * HD + cl0 + tx];
        __syncthreads();
#pragma unroll
        for (int i = 0; i < 4; ++i)
            Wt[(size_t)(wsel * HD + cl0 + ty + i * 8) * IN + k0 + tx] =
                (bf16)Tt[tx][ty + i * 8];
    } else if (tid < 416) {                // Wo 512x64: 16 x 2 tiles
        int t = tid - 384;
        int r0 = (t >> 1) * 32, c0 = (t & 1) * 32;
#pragma unroll
        for (int i = 0; i < 4; ++i)
            Tt[ty + i * 8][tx] = Wo[(size_t)(r0 + ty + i * 8) * D + c0 + tx];
        __syncthreads();
#pragma unroll
        for (int i = 0; i < 4; ++i)
            Wot[(size_t)(c0 + ty + i * 8) * HD + r0 + tx] = (bf16)Tt[tx][ty + i * 8];
    } else {                               // bias concat
        for (int v = threadIdx.x; v < QKV; v += 256)
            bias[v] = v < HD ? bq[v] : (v < 2 * HD ? bk[v - HD] : bv[v - 2 * HD]);
    }
}

// ---------------- QKV projection GEMM (LDS-staged, double-buffered) --------
__global__ __launch_bounds__(256) void qkv_gemm(
    const bf16* __restrict__ A, const bf16* __restrict__ Wt,
    const float* __restrict__ bias,
    bf16* __restrict__ Q, bf16* __restrict__ K, bf16* __restrict__ Vt) {
    __shared__ __align__(16) char smem[65536];  // [2][As 16K|Bs 16K]; epilogue Tv alias
    const int w = threadIdx.x >> 6, lane = threadIdx.x & 63;
    const int lr = lane & 15, lg = lane >> 4;
    const int mblk = blockIdx.x * 128;
    const int m0 = mblk + w * 32;
    const int c0 = blockIdx.y * 128;
    const int swz = (lr & 7) << 4;

    auto stage_step = [&](int buf, int kk) {
        bf16* as_ = (bf16*)(smem + buf * 32768);
        bf16* bs_ = (bf16*)(smem + buf * 32768 + 16384);
#pragma unroll
        for (int j = 0; j < 4; ++j) {
            stage8(A + (size_t)mblk * IN + kk, IN, as_, w * 32 + j * 8, lane);
            stage8(Wt + (size_t)c0 * IN + kk, IN, bs_, w * 32 + j * 8, lane);
        }
    };

    f32x4 acc[2][8] = {};
    stage_step(0, 0);
    __syncthreads();
    int cur = 0;

    for (int kstep = 0; kstep < 4; ++kstep) {
        if (kstep < 3) stage_step(cur ^ 1, (kstep + 1) * 64);
        const char* abase = smem + cur * 32768;
        const char* bbase = abase + 16384;
        const char* arow = abase + (w * 32) * 128;
#pragma unroll
        for (int ks = 0; ks < 2; ++ks) {
            bf16x8 a0 = *(const bf16x8*)(arow + lr * 128 + ((ks * 64 + lg * 16) ^ swz));
            bf16x8 a1 = *(const bf16x8*)(arow + (16 + lr) * 128 + ((ks * 64 + lg * 16) ^ swz));
#pragma unroll
            for (int nt = 0; nt < 8; ++nt) {
                bf16x8 bf = *(const bf16x8*)(bbase + (nt * 16 + lr) * 128 + ((ks * 64 + lg * 16) ^ swz));
                acc[0][nt] = __builtin_amdgcn_mfma_f32_16x16x32_bf16(a0, bf, acc[0][nt], 0, 0, 0);
                acc[1][nt] = __builtin_amdgcn_mfma_f32_16x16x32_bf16(a1, bf, acc[1][nt], 0, 0, 0);
            }
        }
        __syncthreads();
        cur ^= 1;
    }

    if (c0 < 2 * HD) {
        bf16* dst = (c0 < HD) ? Q : K;
#pragma unroll
        for (int mt = 0; mt < 2; ++mt) {
            int rowb = m0 + mt * 16 + lg * 4;
#pragma unroll
            for (int nt = 0; nt < 8; ++nt) {
                int cc = (c0 + nt * 16 + lr) & (HD - 1);
                float bv = bias[c0 + nt * 16 + lr];
                int h = cc >> 6, d = cc & 63;
#pragma unroll
                for (int r = 0; r < 4; ++r) {
                    int row = rowb + r;
                    int b = row >> 11, n = row & (N - 1);
                    dst[(((size_t)(b * H + h) * N) + n) * D + d] =
                        (bf16)(acc[mt][nt][r] + bv);
                }
            }
        }
    } else {
        bf16 (*Tv)[136] = (bf16(*)[136])smem;   // 272B stride: b64/b128 aligned
#pragma unroll
        for (int mt = 0; mt < 2; ++mt) {
            int mb = w * 32 + mt * 16 + lg * 4;
#pragma unroll
            for (int nt = 0; nt < 8; ++nt) {
                int cl = nt * 16 + lr;
                float bv = bias[c0 + cl];
                bf16x4 pk = { (bf16)(acc[mt][nt][0] + bv), (bf16)(acc[mt][nt][1] + bv),
                              (bf16)(acc[mt][nt][2] + bv), (bf16)(acc[mt][nt][3] + bv) };
                *(bf16x4*)&Tv[cl][mb] = pk;
            }
        }
        __syncthreads();
        const int cc0 = c0 - 2 * HD;
        const int b = mblk >> 11;
        const int nb = mblk & (N - 1);
        const int j = threadIdx.x & 15;
#pragma unroll
        for (int pass = 0; pass < 8; ++pass) {
            int cl = pass * 16 + (threadIdx.x >> 4);
            int cc = cc0 + cl, h = cc >> 6, d = cc & 63;
            bf16x8 vv = *(const bf16x8*)&Tv[cl][j * 8];
            *(bf16x8*)(Vt + ((size_t)(b * H + h) * D + d) * N + nb + j * 8) = vv;
        }
    }
}

// ---------------- fused attention v5b ----------------
// v5 structure (per-qt P roundtrip, 48 KB LDS -> 3 blocks/CU) with the
// launch bound back at (512,4): the (512,6) VGPR cap (r12) forced spills
// (VGPR 40, 3.3 GB scratch traffic, 5x slowdown). At VGPR=64 no cap needed.
__global__ __launch_bounds__(512, 4) void attn_kernel(
    const bf16* __restrict__ Qg, const bf16* __restrict__ Kg,
    const bf16* __restrict__ Vtg, bf16* __restrict__ ctx) {
    __shared__ bf16 Kb[2][64][64];   // 16 KB
    __shared__ bf16 Vb[2][64][64];   // 16 KB  (rows d, cols k)
    __shared__ bf16 P[8][16][64];    // 16 KB, XOR-swizzled rows (128B)
    const int w = threadIdx.x >> 6, lane = threadIdx.x & 63;
    const int lr = lane & 15, lg = lane >> 4;
    const int bh = blockIdx.x;
    const int q0 = blockIdx.y * 256 + w * 32;   // wave's 32 q-rows

    const bf16* Qp = Qg + (size_t)bh * N * D;
    const bf16* Kp = Kg + (size_t)bh * N * D;
    const bf16* Vp = Vtg + (size_t)bh * D * N;

    bf16x8 qf[2][2];
#pragma unroll
    for (int qt = 0; qt < 2; ++qt)
#pragma unroll
        for (int kd = 0; kd < 2; ++kd)
            qf[qt][kd] = *(const bf16x8*)(Qp + (size_t)(q0 + qt * 16 + lr) * D + kd * 32 + lg * 8);

    const bf16 onev = (bf16)1.0f;
    const bf16x8 ones = { onev, onev, onev, onev, onev, onev, onev, onev };

    float mrow[2] = { -1e30f, -1e30f };   // running max (lane layout q = lr+16qt)
    float lrow[2][4] = {};                // denom  (cacc layout q = 4*lg+r)
    f32x4 cacc[2][4] = {};                // rows q = 4*lg + r, cols d = dt*16 + lr

    stage8(Kp, 64, &Kb[0][0][0], w * 8, lane);
    stage8(Vp, N,  &Vb[0][0][0], w * 8, lane);
    __syncthreads();
    int cur = 0;

    const int swz = (lr & 7) << 4;
    char* prow0 = (char*)&P[w][lr][0];

    for (int kt = 0; kt < N / 64; ++kt) {
        const int kk0 = kt * 64;
        if (kt + 1 < N / 64) {
            stage8(Kp + (size_t)(kk0 + 64) * 64, 64, &Kb[cur ^ 1][0][0], w * 8, lane);
            stage8(Vp + (kk0 + 64),         N,  &Vb[cur ^ 1][0][0], w * 8, lane);
        }
        const char* kbase = (const char*)&Kb[cur][0][0];
        f32x4 s[2][4] = {};
#pragma unroll
        for (int nt = 0; nt < 4; ++nt)
#pragma unroll
            for (int kd = 0; kd < 2; ++kd) {
                bf16x8 kf = *(const bf16x8*)(kbase + (nt * 16 + lr) * 128 + ((kd * 64 + lg * 16) ^ swz));
                s[0][nt] = __builtin_amdgcn_mfma_f32_16x16x32_bf16(kf, qf[0][kd], s[0][nt], 0, 0, 0);
                s[1][nt] = __builtin_amdgcn_mfma_f32_16x16x32_bf16(kf, qf[1][kd], s[1][nt], 0, 0, 0);
            }
        if (kk0 < q0 + 32 && q0 < kk0 + 64) {
#pragma unroll
            for (int qt = 0; qt < 2; ++qt) {
                int q = q0 + qt * 16 + lr;
#pragma unroll
                for (int nt = 0; nt < 4; ++nt)
#pragma unroll
                    for (int r = 0; r < 4; ++r)
                        if (kk0 + nt * 16 + lg * 4 + r == q) s[qt][nt][r] = -3e38f;
            }
        }
        float rm[2];
        bool need = false;
#pragma unroll
        for (int qt = 0; qt < 2; ++qt) {
            float v = s[qt][0][0];
#pragma unroll
            for (int nt = 0; nt < 4; ++nt)
#pragma unroll
                for (int r = 0; r < 4; ++r) v = fmaxf(v, s[qt][nt][r]);
            v = fmaxf(v, __shfl_xor(v, 16));
            v = fmaxf(v, __shfl_xor(v, 32));
            rm[qt] = v;
            need = need || (v > mrow[qt] + 64.f);
        }
        if (__any(need)) {
#pragma unroll
            for (int qt = 0; qt < 2; ++qt) {
                float mn = fmaxf(mrow[qt], rm[qt]);
                float f = exp2f((mrow[qt] - mn) * SCLOG);
                mrow[qt] = mn;
#pragma unroll
                for (int r = 0; r < 4; ++r) {
                    float fr = __shfl(f, lg * 4 + r);
                    lrow[qt][r] *= fr;
#pragma unroll
                    for (int dt = 0; dt < 4; ++dt) cacc[qt][dt][r] *= fr;
                }
            }
        }
        // ---- per-qt: P -> LDS (16 rows, shared across qt) -> PV MFMAs
        const char* vbase = (const char*)&Vb[cur][0][0];
#pragma unroll
        for (int qt = 0; qt < 2; ++qt) {
            float mc = mrow[qt] * SCLOG;
#pragma unroll
            for (int nt = 0; nt < 4; ++nt) {
                float p0 = exp2f(__builtin_fmaf(s[qt][nt][0], SCLOG, -mc));
                float p1 = exp2f(__builtin_fmaf(s[qt][nt][1], SCLOG, -mc));
                float p2 = exp2f(__builtin_fmaf(s[qt][nt][2], SCLOG, -mc));
                float p3 = exp2f(__builtin_fmaf(s[qt][nt][3], SCLOG, -mc));
                bf16x4 pk = { (bf16)p0, (bf16)p1, (bf16)p2, (bf16)p3 };
                *(bf16x4*)(prow0 + ((nt * 32 + lg * 8) ^ swz)) = pk;
            }
            bf16x8 pa[2];
            f32x4 sacc = {};
#pragma unroll
            for (int ks = 0; ks < 2; ++ks) {
                pa[ks] = *(const bf16x8*)(prow0 + ((ks * 64 + lg * 16) ^ swz));
                sacc = __builtin_amdgcn_mfma_f32_16x16x32_bf16(pa[ks], ones, sacc, 0, 0, 0);
            }
#pragma unroll
            for (int ks = 0; ks < 2; ++ks)
#pragma unroll
                for (int dt = 0; dt < 4; ++dt) {
                    bf16x8 vf = *(const bf16x8*)(vbase + (dt * 16 + lr) * 128 + ((ks * 64 + lg * 16) ^ swz));
                    cacc[qt][dt] = __builtin_amdgcn_mfma_f32_16x16x32_bf16(pa[ks], vf, cacc[qt][dt], 0, 0, 0);
                }
#pragma unroll
            for (int r = 0; r < 4; ++r) lrow[qt][r] += sacc[r];
        }
        __syncthreads();
        cur ^= 1;
    }
    const int b = bh >> 3, h = bh & 7;
#pragma unroll
    for (int qt = 0; qt < 2; ++qt) {
#pragma unroll
        for (int r = 0; r < 4; ++r) {
            float oolr = 1.0f / lrow[qt][r];
            int q = q0 + qt * 16 + lg * 4 + r;
#pragma unroll
            for (int dt = 0; dt < 4; ++dt)
                ctx[((size_t)(b * N + q)) * HD + h * 64 + dt * 16 + lr] =
                    (bf16)(cacc[qt][dt][r] * oolr);
        }
    }
}

// ---------------- output projection ----------------
__global__ __launch_bounds__(256) void out_gemm(
    const bf16* __restrict__ ctx, const bf16* __restrict__ Wot,
    float* __restrict__ out) {
    const int w = threadIdx.x >> 6, lane = threadIdx.x & 63;
    const int lr = lane & 15, lg = lane >> 4;
    const int m0 = blockIdx.x * 64 + w * 16;
    f32x4 acc[4] = {};
#pragma unroll
    for (int ks = 0; ks < 16; ++ks) {
        bf16x8 af = *(const bf16x8*)(ctx + (size_t)(m0 + lr) * HD + ks * 32 + lg * 8);
#pragma unroll
        for (int nt = 0; nt < 4; ++nt) {
            bf16x8 wf = *(const bf16x8*)(Wot + (size_t)(nt * 16 + lr) * HD + ks * 32 + lg * 8);
            acc[nt] = __builtin_amdgcn_mfma_f32_16x16x32_bf16(af, wf, acc[nt], 0, 0, 0);
        }
    }
#pragma unroll
    for (int nt = 0; nt < 4; ++nt)
#pragma unroll
        for (int r = 0; r < 4; ++r)
            out[(size_t)(m0 + lg * 4 + r) * D + nt * 16 + lr] = acc[nt][r];
}

// ---------------- launcher ----------------
extern "C" void kernel_launch(void* const* d_in, const int* in_sizes, int n_in,
                              void* d_out, int out_size, void* d_ws, size_t ws_size,
                              hipStream_t stream) {
    (void)in_sizes; (void)n_in; (void)out_size; (void)ws_size;
    const float* msg = (const float*)d_in[0];
    const float* Wq  = (const float*)d_in[1];
    const float* bq  = (const float*)d_in[2];
    const float* Wk  = (const float*)d_in[3];
    const float* bk  = (const float*)d_in[4];
    const float* Wv  = (const float*)d_in[5];
    const float* bv  = (const float*)d_in[6];
    const float* Wo  = (const float*)d_in[7];
    float* out = (float*)d_out;

    char* p = (char*)d_ws;
    bf16*  Abf  = (bf16*)p;  p += (size_t)M * IN * 2;      // 8 MB
    bf16*  Wt   = (bf16*)p;  p += (size_t)QKV * IN * 2;    // 768 KB
    float* bias = (float*)p; p += (size_t)QKV * 4;         // 6 KB
    bf16*  Wot  = (bf16*)p;  p += (size_t)D * HD * 2;      // 64 KB
    bf16*  Qb   = (bf16*)p;  p += (size_t)Bsz * H * N * D * 2;   // 16 MB
    bf16*  Kb   = (bf16*)p;  p += (size_t)Bsz * H * N * D * 2;   // 16 MB
    bf16*  Vtb  = (bf16*)p;  p += (size_t)Bsz * H * D * N * 2;   // 16 MB
    bf16*  Ctx  = (bf16*)p;  p += (size_t)M * HD * 2;            // 16 MB

    cvt_msg<<<(M * IN / 4) / 256, 256, 0, stream>>>(msg, Abf);
    pack_w<<<417, 256, 0, stream>>>(Wq, Wk, Wv, bq, bk, bv, Wo, Wt, bias, Wot);

    dim3 g1(M / 128, QKV / 128);     // 128 x 12
    qkv_gemm<<<g1, 256, 0, stream>>>(Abf, Wt, bias, Qb, Kb, Vtb);

    dim3 g2(Bsz * H, N / 256);       // 64 x 8 : 512 blocks, 3/CU
    attn_kernel<<<g2, 512, 0, stream>>>(Qb, Kb, Vtb, Ctx);

    out_gemm<<<M / 64, 256, 0, stream>>>(Ctx, Wot, out);
}

// Round 14
// 241.338 us; speedup vs baseline: 3.2999x; 1.0925x over previous
//
#include <hip/hip_runtime.h>

typedef __bf16 bf16;
typedef __bf16 bf16x4 __attribute__((ext_vector_type(4)));
typedef __bf16 bf16x8 __attribute__((ext_vector_type(8)));
typedef float f32x4 __attribute__((ext_vector_type(4)));

#define SCLOG 0.1803368801111244f   // 0.125 * log2(e)

constexpr int Bsz = 8, N = 2048, IN = 256, H = 8, D = 64;
constexpr int M = Bsz * N;       // 16384 rows
constexpr int HD = H * D;        // 512
constexpr int QKV = 3 * HD;      // 1536

// Stage 8 rows x 64 cols (bf16) into LDS via global_load_lds, 16B/lane.
// LDS dest linear; source column pre-swizzled (XOR r8) so swizzled ds_reads
// land conflict-free (both-sides rule): LDS[row][c] = G[row][c ^ ((row&7)<<4)].
__device__ __forceinline__ void stage8(const bf16* __restrict__ src, size_t stride,
                                       bf16* ldsBase, int row0, int lane) {
    int r8 = lane >> 3;
    int cb = ((lane & 7) ^ r8) << 4;
    const bf16* g = src + (size_t)(row0 + r8) * stride + (cb >> 1);
    bf16* l = ldsBase + row0 * 64;
    __builtin_amdgcn_global_load_lds(
        (const __attribute__((address_space(1))) char*)g,
        (__attribute__((address_space(3))) char*)l, 16, 0, 0);
}

// ---------------- pack_w: tiled transposes + bias concat ----------------
__global__ __launch_bounds__(256) void pack_w(
    const float* __restrict__ Wq, const float* __restrict__ Wk,
    const float* __restrict__ Wv, const float* __restrict__ bq,
    const float* __restrict__ bk, const float* __restrict__ bv,
    const float* __restrict__ Wo,
    bf16* __restrict__ Wt, float* __restrict__ bias, bf16* __restrict__ Wot) {
    __shared__ float Tt[32][33];
    const int tid = blockIdx.x;
    const int tx = threadIdx.x & 31, ty = threadIdx.x >> 5;   // 32 x 8
    if (tid < 384) {
        int wsel = tid >> 7, t = tid & 127;
        int k0 = (t >> 4) * 32, cl0 = (t & 15) * 32;
        const float* W = wsel == 0 ? Wq : (wsel == 1 ? Wk : Wv);
#pragma unroll
        for (int i = 0; i < 4; ++i)
            Tt[ty + i * 8][tx] = W[(size_t)(k0 + ty + i * 8) * HD + cl0 + tx];
        __syncthreads();
#pragma unroll
        for (int i = 0; i < 4; ++i)
            Wt[(size_t)(wsel * HD + cl0 + ty + i * 8) * IN + k0 + tx] =
                (bf16)Tt[tx][ty + i * 8];
    } else if (tid < 416) {
        int t = tid - 384;
        int r0 = (t >> 1) * 32, c0 = (t & 1) * 32;
#pragma unroll
        for (int i = 0; i < 4; ++i)
            Tt[ty + i * 8][tx] = Wo[(size_t)(r0 + ty + i * 8) * D + c0 + tx];
        __syncthreads();
#pragma unroll
        for (int i = 0; i < 4; ++i)
            Wot[(size_t)(c0 + ty + i * 8) * HD + r0 + tx] = (bf16)Tt[tx][ty + i * 8];
    } else {
        for (int v = threadIdx.x; v < QKV; v += 256)
            bias[v] = v < HD ? bq[v] : (v < 2 * HD ? bk[v - HD] : bv[v - 2 * HD]);
    }
}

// ---------------- QKV projection GEMM (fused fp32->bf16 A-staging) --------
// A staged from msg (fp32) via reg-convert + swizzled ds_write_b64, producing
// the SAME LDS image as stage8 would. B (Wt) staged via global_load_lds.
__global__ __launch_bounds__(256) void qkv_gemm(
    const float* __restrict__ msg, const bf16* __restrict__ Wt,
    const float* __restrict__ bias,
    bf16* __restrict__ Q, bf16* __restrict__ K, bf16* __restrict__ Vt) {
    __shared__ __align__(16) char smem[65536];  // [2][As 16K|Bs 16K]; epilogue Tv alias
    const int w = threadIdx.x >> 6, lane = threadIdx.x & 63;
    const int lr = lane & 15, lg = lane >> 4;
    const int mblk = blockIdx.x * 128;
    const int m0 = mblk + w * 32;
    const int c0 = blockIdx.y * 128;
    const int swz = (lr & 7) << 4;

    // A-staging thread mapping: t -> row = t>>1 (128 rows), col half = (t&1)*32
    const int arow = threadIdx.x >> 1;
    const int ach = (threadIdx.x & 1) * 32;
    const int aswz = (arow & 7) << 4;
    const float* amsg = msg + (size_t)(mblk + arow) * IN + ach;

    auto stage_step = [&](int buf, int kk) {
        bf16* bs_ = (bf16*)(smem + buf * 32768 + 16384);
#pragma unroll
        for (int j = 0; j < 4; ++j)
            stage8(Wt + (size_t)c0 * IN + kk, IN, bs_, w * 32 + j * 8, lane);
        char* arow_lds = smem + buf * 32768 + arow * 128;
#pragma unroll
        for (int j = 0; j < 8; ++j) {
            float4 v = *(const float4*)(amsg + kk + j * 4);
            bf16x4 o = { (bf16)v.x, (bf16)v.y, (bf16)v.z, (bf16)v.w };
            *(bf16x4*)(arow_lds + (((ach + j * 4) * 2) ^ aswz)) = o;
        }
    };

    f32x4 acc[2][8] = {};
    stage_step(0, 0);
    __syncthreads();
    int cur = 0;

    for (int kstep = 0; kstep < 4; ++kstep) {
        if (kstep < 3) stage_step(cur ^ 1, (kstep + 1) * 64);
        const char* abase = smem + cur * 32768;
        const char* bbase = abase + 16384;
        const char* arow_ = abase + (w * 32) * 128;
#pragma unroll
        for (int ks = 0; ks < 2; ++ks) {
            bf16x8 a0 = *(const bf16x8*)(arow_ + lr * 128 + ((ks * 64 + lg * 16) ^ swz));
            bf16x8 a1 = *(const bf16x8*)(arow_ + (16 + lr) * 128 + ((ks * 64 + lg * 16) ^ swz));
#pragma unroll
            for (int nt = 0; nt < 8; ++nt) {
                bf16x8 bf = *(const bf16x8*)(bbase + (nt * 16 + lr) * 128 + ((ks * 64 + lg * 16) ^ swz));
                acc[0][nt] = __builtin_amdgcn_mfma_f32_16x16x32_bf16(a0, bf, acc[0][nt], 0, 0, 0);
                acc[1][nt] = __builtin_amdgcn_mfma_f32_16x16x32_bf16(a1, bf, acc[1][nt], 0, 0, 0);
            }
        }
        __syncthreads();
        cur ^= 1;
    }

    if (c0 < 2 * HD) {
        bf16* dst = (c0 < HD) ? Q : K;
#pragma unroll
        for (int mt = 0; mt < 2; ++mt) {
            int rowb = m0 + mt * 16 + lg * 4;
#pragma unroll
            for (int nt = 0; nt < 8; ++nt) {
                int cc = (c0 + nt * 16 + lr) & (HD - 1);
                float bv = bias[c0 + nt * 16 + lr];
                int h = cc >> 6, d = cc & 63;
#pragma unroll
                for (int r = 0; r < 4; ++r) {
                    int row = rowb + r;
                    int b = row >> 11, n = row & (N - 1);
                    dst[(((size_t)(b * H + h) * N) + n) * D + d] =
                        (bf16)(acc[mt][nt][r] + bv);
                }
            }
        }
    } else {
        bf16 (*Tv)[136] = (bf16(*)[136])smem;   // 272B stride: b64/b128 aligned
#pragma unroll
        for (int mt = 0; mt < 2; ++mt) {
            int mb = w * 32 + mt * 16 + lg * 4;
#pragma unroll
            for (int nt = 0; nt < 8; ++nt) {
                int cl = nt * 16 + lr;
                float bv = bias[c0 + cl];
                bf16x4 pk = { (bf16)(acc[mt][nt][0] + bv), (bf16)(acc[mt][nt][1] + bv),
                              (bf16)(acc[mt][nt][2] + bv), (bf16)(acc[mt][nt][3] + bv) };
                *(bf16x4*)&Tv[cl][mb] = pk;
            }
        }
        __syncthreads();
        const int cc0 = c0 - 2 * HD;
        const int b = mblk >> 11;
        const int nb = mblk & (N - 1);
        const int j = threadIdx.x & 15;
#pragma unroll
        for (int pass = 0; pass < 8; ++pass) {
            int cl = pass * 16 + (threadIdx.x >> 4);
            int cc = cc0 + cl, h = cc >> 6, d = cc & 63;
            bf16x8 vv = *(const bf16x8*)&Tv[cl][j * 8];
            *(bf16x8*)(Vt + ((size_t)(b * H + h) * D + d) * N + nb + j * 8) = vv;
        }
    }
}

// ---------------- fused attention v4r (round-11 structure, reverted) -------
// Known-best: 128 us. Per-qt v5 roundtrip regressed (r13: serial LDS chain).
// Only change vs r11: rowmax uses a max3-shaped tree (compiler fuses fmax
// pairs into v_max3) instead of a 15-op serial chain.
__global__ __launch_bounds__(512, 4) void attn_kernel(
    const bf16* __restrict__ Qg, const bf16* __restrict__ Kg,
    const bf16* __restrict__ Vtg, bf16* __restrict__ ctx) {
    __shared__ bf16 Kb[2][64][64];   // 16 KB
    __shared__ bf16 Vb[2][64][64];   // 16 KB  (rows d, cols k)
    __shared__ bf16 P[8][32][64];    // 32 KB, XOR-swizzled rows (128B)
    const int w = threadIdx.x >> 6, lane = threadIdx.x & 63;
    const int lr = lane & 15, lg = lane >> 4;
    const int bh = blockIdx.x;
    const int q0 = blockIdx.y * 256 + w * 32;   // wave's 32 q-rows

    const bf16* Qp = Qg + (size_t)bh * N * D;
    const bf16* Kp = Kg + (size_t)bh * N * D;
    const bf16* Vp = Vtg + (size_t)bh * D * N;

    bf16x8 qf[2][2];
#pragma unroll
    for (int qt = 0; qt < 2; ++qt)
#pragma unroll
        for (int kd = 0; kd < 2; ++kd)
            qf[qt][kd] = *(const bf16x8*)(Qp + (size_t)(q0 + qt * 16 + lr) * D + kd * 32 + lg * 8);

    const bf16 onev = (bf16)1.0f;
    const bf16x8 ones = { onev, onev, onev, onev, onev, onev, onev, onev };

    float mrow[2] = { -1e30f, -1e30f };   // running max (lane layout q = lr+16qt)
    float lrow[2][4] = {};                // denom  (cacc layout q = 4*lg+r)
    f32x4 cacc[2][4] = {};                // rows q = 4*lg + r, cols d = dt*16 + lr

    stage8(Kp, 64, &Kb[0][0][0], w * 8, lane);
    stage8(Vp, N,  &Vb[0][0][0], w * 8, lane);
    __syncthreads();
    int cur = 0;

    const int swz = (lr & 7) << 4;
    char* prow0 = (char*)&P[w][lr][0];

    for (int kt = 0; kt < N / 64; ++kt) {
        const int kk0 = kt * 64;
        if (kt + 1 < N / 64) {
            stage8(Kp + (size_t)(kk0 + 64) * 64, 64, &Kb[cur ^ 1][0][0], w * 8, lane);
            stage8(Vp + (kk0 + 64),         N,  &Vb[cur ^ 1][0][0], w * 8, lane);
        }
        const char* kbase = (const char*)&Kb[cur][0][0];
        f32x4 s[2][4] = {};
#pragma unroll
        for (int nt = 0; nt < 4; ++nt)
#pragma unroll
            for (int kd = 0; kd < 2; ++kd) {
                bf16x8 kf = *(const bf16x8*)(kbase + (nt * 16 + lr) * 128 + ((kd * 64 + lg * 16) ^ swz));
                s[0][nt] = __builtin_amdgcn_mfma_f32_16x16x32_bf16(kf, qf[0][kd], s[0][nt], 0, 0, 0);
                s[1][nt] = __builtin_amdgcn_mfma_f32_16x16x32_bf16(kf, qf[1][kd], s[1][nt], 0, 0, 0);
            }
        if (kk0 < q0 + 32 && q0 < kk0 + 64) {
#pragma unroll
            for (int qt = 0; qt < 2; ++qt) {
                int q = q0 + qt * 16 + lr;
#pragma unroll
                for (int nt = 0; nt < 4; ++nt)
#pragma unroll
                    for (int r = 0; r < 4; ++r)
                        if (kk0 + nt * 16 + lg * 4 + r == q) s[qt][nt][r] = -3e38f;
            }
        }
        float rm[2];
        bool need = false;
#pragma unroll
        for (int qt = 0; qt < 2; ++qt) {
            // max3-shaped tree over 16 values (clang fuses fmax pairs to v_max3)
            float a0 = fmaxf(fmaxf(s[qt][0][0], s[qt][0][1]), s[qt][0][2]);
            float a1 = fmaxf(fmaxf(s[qt][0][3], s[qt][1][0]), s[qt][1][1]);
            float a2 = fmaxf(fmaxf(s[qt][1][2], s[qt][1][3]), s[qt][2][0]);
            float a3 = fmaxf(fmaxf(s[qt][2][1], s[qt][2][2]), s[qt][2][3]);
            float a4 = fmaxf(fmaxf(s[qt][3][0], s[qt][3][1]), s[qt][3][2]);
            float v = fmaxf(fmaxf(fmaxf(a0, a1), fmaxf(a2, a3)),
                            fmaxf(a4, s[qt][3][3]));
            v = fmaxf(v, __shfl_xor(v, 16));
            v = fmaxf(v, __shfl_xor(v, 32));
            rm[qt] = v;
            need = need || (v > mrow[qt] + 64.f);
        }
        if (__any(need)) {
#pragma unroll
            for (int qt = 0; qt < 2; ++qt) {
                float mn = fmaxf(mrow[qt], rm[qt]);
                float f = exp2f((mrow[qt] - mn) * SCLOG);
                mrow[qt] = mn;
#pragma unroll
                for (int r = 0; r < 4; ++r) {
                    float fr = __shfl(f, lg * 4 + r);
                    lrow[qt][r] *= fr;
#pragma unroll
                    for (int dt = 0; dt < 4; ++dt) cacc[qt][dt][r] *= fr;
                }
            }
        }
        // ---- P = exp2((s - m)*SCLOG), pack b64 to LDS (swizzled)
#pragma unroll
        for (int qt = 0; qt < 2; ++qt) {
            float mc = mrow[qt] * SCLOG;
            char* prow = prow0 + qt * 2048;
#pragma unroll
            for (int nt = 0; nt < 4; ++nt) {
                float p0 = exp2f(__builtin_fmaf(s[qt][nt][0], SCLOG, -mc));
                float p1 = exp2f(__builtin_fmaf(s[qt][nt][1], SCLOG, -mc));
                float p2 = exp2f(__builtin_fmaf(s[qt][nt][2], SCLOG, -mc));
                float p3 = exp2f(__builtin_fmaf(s[qt][nt][3], SCLOG, -mc));
                bf16x4 pk = { (bf16)p0, (bf16)p1, (bf16)p2, (bf16)p3 };
                *(bf16x4*)(prow + ((nt * 32 + lg * 8) ^ swz)) = pk;
            }
        }
        // ---- ctx += P V ; row-sums via ones-MFMA
        const char* vbase = (const char*)&Vb[cur][0][0];
        f32x4 sacc[2] = {};
#pragma unroll
        for (int ks = 0; ks < 2; ++ks) {
            bf16x8 pa[2];
#pragma unroll
            for (int qt = 0; qt < 2; ++qt) {
                pa[qt] = *(const bf16x8*)(prow0 + qt * 2048 + ((ks * 64 + lg * 16) ^ swz));
                sacc[qt] = __builtin_amdgcn_mfma_f32_16x16x32_bf16(pa[qt], ones, sacc[qt], 0, 0, 0);
            }
#pragma unroll
            for (int dt = 0; dt < 4; ++dt) {
                bf16x8 vf = *(const bf16x8*)(vbase + (dt * 16 + lr) * 128 + ((ks * 64 + lg * 16) ^ swz));
                cacc[0][dt] = __builtin_amdgcn_mfma_f32_16x16x32_bf16(pa[0], vf, cacc[0][dt], 0, 0, 0);
                cacc[1][dt] = __builtin_amdgcn_mfma_f32_16x16x32_bf16(pa[1], vf, cacc[1][dt], 0, 0, 0);
            }
        }
#pragma unroll
        for (int qt = 0; qt < 2; ++qt)
#pragma unroll
            for (int r = 0; r < 4; ++r) lrow[qt][r] += sacc[qt][r];
        __syncthreads();
        cur ^= 1;
    }
    const int b = bh >> 3, h = bh & 7;
#pragma unroll
    for (int qt = 0; qt < 2; ++qt) {
#pragma unroll
        for (int r = 0; r < 4; ++r) {
            float oolr = 1.0f / lrow[qt][r];
            int q = q0 + qt * 16 + lg * 4 + r;
#pragma unroll
            for (int dt = 0; dt < 4; ++dt)
                ctx[((size_t)(b * N + q)) * HD + h * 64 + dt * 16 + lr] =
                    (bf16)(cacc[qt][dt][r] * oolr);
        }
    }
}

// ---------------- output projection ----------------
__global__ __launch_bounds__(256) void out_gemm(
    const bf16* __restrict__ ctx, const bf16* __restrict__ Wot,
    float* __restrict__ out) {
    const int w = threadIdx.x >> 6, lane = threadIdx.x & 63;
    const int lr = lane & 15, lg = lane >> 4;
    const int m0 = blockIdx.x * 64 + w * 16;
    f32x4 acc[4] = {};
#pragma unroll
    for (int ks = 0; ks < 16; ++ks) {
        bf16x8 af = *(const bf16x8*)(ctx + (size_t)(m0 + lr) * HD + ks * 32 + lg * 8);
#pragma unroll
        for (int nt = 0; nt < 4; ++nt) {
            bf16x8 wf = *(const bf16x8*)(Wot + (size_t)(nt * 16 + lr) * HD + ks * 32 + lg * 8);
            acc[nt] = __builtin_amdgcn_mfma_f32_16x16x32_bf16(af, wf, acc[nt], 0, 0, 0);
        }
    }
#pragma unroll
    for (int nt = 0; nt < 4; ++nt)
#pragma unroll
        for (int r = 0; r < 4; ++r)
            out[(size_t)(m0 + lg * 4 + r) * D + nt * 16 + lr] = acc[nt][r];
}

// ---------------- launcher ----------------
extern "C" void kernel_launch(void* const* d_in, const int* in_sizes, int n_in,
                              void* d_out, int out_size, void* d_ws, size_t ws_size,
                              hipStream_t stream) {
    (void)in_sizes; (void)n_in; (void)out_size; (void)ws_size;
    const float* msg = (const float*)d_in[0];
    const float* Wq  = (const float*)d_in[1];
    const float* bq  = (const float*)d_in[2];
    const float* Wk  = (const float*)d_in[3];
    const float* bk  = (const float*)d_in[4];
    const float* Wv  = (const float*)d_in[5];
    const float* bv  = (const float*)d_in[6];
    const float* Wo  = (const float*)d_in[7];
    float* out = (float*)d_out;

    char* p = (char*)d_ws;
    bf16*  Wt   = (bf16*)p;  p += (size_t)QKV * IN * 2;    // 768 KB
    float* bias = (float*)p; p += (size_t)QKV * 4;         // 6 KB
    bf16*  Wot  = (bf16*)p;  p += (size_t)D * HD * 2;      // 64 KB
    bf16*  Qb   = (bf16*)p;  p += (size_t)Bsz * H * N * D * 2;   // 16 MB
    bf16*  Kb   = (bf16*)p;  p += (size_t)Bsz * H * N * D * 2;   // 16 MB
    bf16*  Vtb  = (bf16*)p;  p += (size_t)Bsz * H * D * N * 2;   // 16 MB
    bf16*  Ctx  = (bf16*)p;  p += (size_t)M * HD * 2;            // 16 MB

    pack_w<<<417, 256, 0, stream>>>(Wq, Wk, Wv, bq, bk, bv, Wo, Wt, bias, Wot);

    dim3 g1(M / 128, QKV / 128);     // 128 x 12
    qkv_gemm<<<g1, 256, 0, stream>>>(msg, Wt, bias, Qb, Kb, Vtb);

    dim3 g2(Bsz * H, N / 256);       // 64 x 8 : 512 blocks, 2/CU
    attn_kernel<<<g2, 512, 0, stream>>>(Qb, Kb, Vtb, Ctx);

    out_gemm<<<M / 64, 256, 0, stream>>>(Ctx, Wot, out);
}

// Round 15
// 227.339 us; speedup vs baseline: 3.5031x; 1.0616x over previous
//
#include <hip/hip_runtime.h>

typedef __bf16 bf16;
typedef __bf16 bf16x4 __attribute__((ext_vector_type(4)));
typedef __bf16 bf16x8 __attribute__((ext_vector_type(8)));
typedef float f32x4 __attribute__((ext_vector_type(4)));

#define SCLOG 0.1803368801111244f   // 0.125 * log2(e)

constexpr int Bsz = 8, N = 2048, IN = 256, H = 8, D = 64;
constexpr int M = Bsz * N;       // 16384 rows
constexpr int HD = H * D;        // 512
constexpr int QKV = 3 * HD;      // 1536

// Stage 8 rows x 64 cols (bf16) into LDS via global_load_lds, 16B/lane.
// LDS dest linear; source column pre-swizzled (XOR r8) so swizzled ds_reads
// land conflict-free (both-sides rule): LDS[row][c] = G[row][c ^ ((row&7)<<4)].
__device__ __forceinline__ void stage8(const bf16* __restrict__ src, size_t stride,
                                       bf16* ldsBase, int row0, int lane) {
    int r8 = lane >> 3;
    int cb = ((lane & 7) ^ r8) << 4;
    const bf16* g = src + (size_t)(row0 + r8) * stride + (cb >> 1);
    bf16* l = ldsBase + row0 * 64;
    __builtin_amdgcn_global_load_lds(
        (const __attribute__((address_space(1))) char*)g,
        (__attribute__((address_space(3))) char*)l, 16, 0, 0);
}

// ---------------- prep kernels (r11 config: cvt once, bf16 staging) --------
__global__ void cvt_msg(const float* __restrict__ in, bf16* __restrict__ out) {
    int i = blockIdx.x * blockDim.x + threadIdx.x;   // one float4 per thread
    float4 v = ((const float4*)in)[i];
    bf16x4 o = { (bf16)v.x, (bf16)v.y, (bf16)v.z, (bf16)v.w };
    ((bf16x4*)out)[i] = o;
}

__global__ __launch_bounds__(256) void pack_w(
    const float* __restrict__ Wq, const float* __restrict__ Wk,
    const float* __restrict__ Wv, const float* __restrict__ bq,
    const float* __restrict__ bk, const float* __restrict__ bv,
    const float* __restrict__ Wo,
    bf16* __restrict__ Wt, float* __restrict__ bias, bf16* __restrict__ Wot) {
    __shared__ float Tt[32][33];
    const int tid = blockIdx.x;
    const int tx = threadIdx.x & 31, ty = threadIdx.x >> 5;   // 32 x 8
    if (tid < 384) {
        int wsel = tid >> 7, t = tid & 127;
        int k0 = (t >> 4) * 32, cl0 = (t & 15) * 32;
        const float* W = wsel == 0 ? Wq : (wsel == 1 ? Wk : Wv);
#pragma unroll
        for (int i = 0; i < 4; ++i)
            Tt[ty + i * 8][tx] = W[(size_t)(k0 + ty + i * 8) * HD + cl0 + tx];
        __syncthreads();
#pragma unroll
        for (int i = 0; i < 4; ++i)
            Wt[(size_t)(wsel * HD + cl0 + ty + i * 8) * IN + k0 + tx] =
                (bf16)Tt[tx][ty + i * 8];
    } else if (tid < 416) {
        int t = tid - 384;
        int r0 = (t >> 1) * 32, c0 = (t & 1) * 32;
#pragma unroll
        for (int i = 0; i < 4; ++i)
            Tt[ty + i * 8][tx] = Wo[(size_t)(r0 + ty + i * 8) * D + c0 + tx];
        __syncthreads();
#pragma unroll
        for (int i = 0; i < 4; ++i)
            Wot[(size_t)(c0 + ty + i * 8) * HD + r0 + tx] = (bf16)Tt[tx][ty + i * 8];
    } else {
        for (int v = threadIdx.x; v < QKV; v += 256)
            bias[v] = v < HD ? bq[v] : (v < 2 * HD ? bk[v - HD] : bv[v - 2 * HD]);
    }
}

// ---------------- QKV projection GEMM (r11: bf16 A via global_load_lds) ----
__global__ __launch_bounds__(256) void qkv_gemm(
    const bf16* __restrict__ A, const bf16* __restrict__ Wt,
    const float* __restrict__ bias,
    bf16* __restrict__ Q, bf16* __restrict__ K, bf16* __restrict__ Vt) {
    __shared__ __align__(16) char smem[65536];  // [2][As 16K|Bs 16K]; epilogue Tv alias
    const int w = threadIdx.x >> 6, lane = threadIdx.x & 63;
    const int lr = lane & 15, lg = lane >> 4;
    const int mblk = blockIdx.x * 128;
    const int m0 = mblk + w * 32;
    const int c0 = blockIdx.y * 128;
    const int swz = (lr & 7) << 4;

    auto stage_step = [&](int buf, int kk) {
        bf16* as_ = (bf16*)(smem + buf * 32768);
        bf16* bs_ = (bf16*)(smem + buf * 32768 + 16384);
#pragma unroll
        for (int j = 0; j < 4; ++j) {
            stage8(A + (size_t)mblk * IN + kk, IN, as_, w * 32 + j * 8, lane);
            stage8(Wt + (size_t)c0 * IN + kk, IN, bs_, w * 32 + j * 8, lane);
        }
    };

    f32x4 acc[2][8] = {};
    stage_step(0, 0);
    __syncthreads();
    int cur = 0;

    for (int kstep = 0; kstep < 4; ++kstep) {
        if (kstep < 3) stage_step(cur ^ 1, (kstep + 1) * 64);
        const char* abase = smem + cur * 32768;
        const char* bbase = abase + 16384;
        const char* arow = abase + (w * 32) * 128;
#pragma unroll
        for (int ks = 0; ks < 2; ++ks) {
            bf16x8 a0 = *(const bf16x8*)(arow + lr * 128 + ((ks * 64 + lg * 16) ^ swz));
            bf16x8 a1 = *(const bf16x8*)(arow + (16 + lr) * 128 + ((ks * 64 + lg * 16) ^ swz));
#pragma unroll
            for (int nt = 0; nt < 8; ++nt) {
                bf16x8 bf = *(const bf16x8*)(bbase + (nt * 16 + lr) * 128 + ((ks * 64 + lg * 16) ^ swz));
                acc[0][nt] = __builtin_amdgcn_mfma_f32_16x16x32_bf16(a0, bf, acc[0][nt], 0, 0, 0);
                acc[1][nt] = __builtin_amdgcn_mfma_f32_16x16x32_bf16(a1, bf, acc[1][nt], 0, 0, 0);
            }
        }
        __syncthreads();
        cur ^= 1;
    }

    if (c0 < 2 * HD) {
        bf16* dst = (c0 < HD) ? Q : K;
#pragma unroll
        for (int mt = 0; mt < 2; ++mt) {
            int rowb = m0 + mt * 16 + lg * 4;
#pragma unroll
            for (int nt = 0; nt < 8; ++nt) {
                int cc = (c0 + nt * 16 + lr) & (HD - 1);
                float bv = bias[c0 + nt * 16 + lr];
                int h = cc >> 6, d = cc & 63;
#pragma unroll
                for (int r = 0; r < 4; ++r) {
                    int row = rowb + r;
                    int b = row >> 11, n = row & (N - 1);
                    dst[(((size_t)(b * H + h) * N) + n) * D + d] =
                        (bf16)(acc[mt][nt][r] + bv);
                }
            }
        }
    } else {
        bf16 (*Tv)[136] = (bf16(*)[136])smem;   // 272B stride: b64/b128 aligned
#pragma unroll
        for (int mt = 0; mt < 2; ++mt) {
            int mb = w * 32 + mt * 16 + lg * 4;
#pragma unroll
            for (int nt = 0; nt < 8; ++nt) {
                int cl = nt * 16 + lr;
                float bv = bias[c0 + cl];
                bf16x4 pk = { (bf16)(acc[mt][nt][0] + bv), (bf16)(acc[mt][nt][1] + bv),
                              (bf16)(acc[mt][nt][2] + bv), (bf16)(acc[mt][nt][3] + bv) };
                *(bf16x4*)&Tv[cl][mb] = pk;
            }
        }
        __syncthreads();
        const int cc0 = c0 - 2 * HD;
        const int b = mblk >> 11;
        const int nb = mblk & (N - 1);
        const int j = threadIdx.x & 15;
#pragma unroll
        for (int pass = 0; pass < 8; ++pass) {
            int cl = pass * 16 + (threadIdx.x >> 4);
            int cc = cc0 + cl, h = cc >> 6, d = cc & 63;
            bf16x8 vv = *(const bf16x8*)&Tv[cl][j * 8];
            *(bf16x8*)(Vt + ((size_t)(b * H + h) * D + d) * N + nb + j * 8) = vv;
        }
    }
}

// ---------------- fused attention v4 (r11 exact — validated best 128us) ----
__global__ __launch_bounds__(512, 4) void attn_kernel(
    const bf16* __restrict__ Qg, const bf16* __restrict__ Kg,
    const bf16* __restrict__ Vtg, bf16* __restrict__ ctx) {
    __shared__ bf16 Kb[2][64][64];   // 16 KB
    __shared__ bf16 Vb[2][64][64];   // 16 KB  (rows d, cols k)
    __shared__ bf16 P[8][32][64];    // 32 KB, XOR-swizzled rows (128B)
    const int w = threadIdx.x >> 6, lane = threadIdx.x & 63;
    const int lr = lane & 15, lg = lane >> 4;
    const int bh = blockIdx.x;
    const int q0 = blockIdx.y * 256 + w * 32;   // wave's 32 q-rows

    const bf16* Qp = Qg + (size_t)bh * N * D;
    const bf16* Kp = Kg + (size_t)bh * N * D;
    const bf16* Vp = Vtg + (size_t)bh * D * N;

    bf16x8 qf[2][2];
#pragma unroll
    for (int qt = 0; qt < 2; ++qt)
#pragma unroll
        for (int kd = 0; kd < 2; ++kd)
            qf[qt][kd] = *(const bf16x8*)(Qp + (size_t)(q0 + qt * 16 + lr) * D + kd * 32 + lg * 8);

    const bf16 onev = (bf16)1.0f;
    const bf16x8 ones = { onev, onev, onev, onev, onev, onev, onev, onev };

    float mrow[2] = { -1e30f, -1e30f };   // running max (lane layout q = lr+16qt)
    float lrow[2][4] = {};                // denom  (cacc layout q = 4*lg+r)
    f32x4 cacc[2][4] = {};                // rows q = 4*lg + r, cols d = dt*16 + lr

    stage8(Kp, 64, &Kb[0][0][0], w * 8, lane);
    stage8(Vp, N,  &Vb[0][0][0], w * 8, lane);
    __syncthreads();
    int cur = 0;

    const int swz = (lr & 7) << 4;
    char* prow0 = (char*)&P[w][lr][0];

    for (int kt = 0; kt < N / 64; ++kt) {
        const int kk0 = kt * 64;
        if (kt + 1 < N / 64) {
            stage8(Kp + (size_t)(kk0 + 64) * 64, 64, &Kb[cur ^ 1][0][0], w * 8, lane);
            stage8(Vp + (kk0 + 64),         N,  &Vb[cur ^ 1][0][0], w * 8, lane);
        }
        const char* kbase = (const char*)&Kb[cur][0][0];
        f32x4 s[2][4] = {};
#pragma unroll
        for (int nt = 0; nt < 4; ++nt)
#pragma unroll
            for (int kd = 0; kd < 2; ++kd) {
                bf16x8 kf = *(const bf16x8*)(kbase + (nt * 16 + lr) * 128 + ((kd * 64 + lg * 16) ^ swz));
                s[0][nt] = __builtin_amdgcn_mfma_f32_16x16x32_bf16(kf, qf[0][kd], s[0][nt], 0, 0, 0);
                s[1][nt] = __builtin_amdgcn_mfma_f32_16x16x32_bf16(kf, qf[1][kd], s[1][nt], 0, 0, 0);
            }
        if (kk0 < q0 + 32 && q0 < kk0 + 64) {
#pragma unroll
            for (int qt = 0; qt < 2; ++qt) {
                int q = q0 + qt * 16 + lr;
#pragma unroll
                for (int nt = 0; nt < 4; ++nt)
#pragma unroll
                    for (int r = 0; r < 4; ++r)
                        if (kk0 + nt * 16 + lg * 4 + r == q) s[qt][nt][r] = -3e38f;
            }
        }
        float rm[2];
        bool need = false;
#pragma unroll
        for (int qt = 0; qt < 2; ++qt) {
            float v = s[qt][0][0];
#pragma unroll
            for (int nt = 0; nt < 4; ++nt)
#pragma unroll
                for (int r = 0; r < 4; ++r) v = fmaxf(v, s[qt][nt][r]);
            v = fmaxf(v, __shfl_xor(v, 16));
            v = fmaxf(v, __shfl_xor(v, 32));
            rm[qt] = v;
            need = need || (v > mrow[qt] + 64.f);
        }
        if (__any(need)) {
#pragma unroll
            for (int qt = 0; qt < 2; ++qt) {
                float mn = fmaxf(mrow[qt], rm[qt]);
                float f = exp2f((mrow[qt] - mn) * SCLOG);
                mrow[qt] = mn;
#pragma unroll
                for (int r = 0; r < 4; ++r) {
                    float fr = __shfl(f, lg * 4 + r);
                    lrow[qt][r] *= fr;
#pragma unroll
                    for (int dt = 0; dt < 4; ++dt) cacc[qt][dt][r] *= fr;
                }
            }
        }
        // ---- P = exp2((s - m)*SCLOG), pack b64 to LDS (swizzled)
#pragma unroll
        for (int qt = 0; qt < 2; ++qt) {
            float mc = mrow[qt] * SCLOG;
            char* prow = prow0 + qt * 2048;
#pragma unroll
            for (int nt = 0; nt < 4; ++nt) {
                float p0 = exp2f(__builtin_fmaf(s[qt][nt][0], SCLOG, -mc));
                float p1 = exp2f(__builtin_fmaf(s[qt][nt][1], SCLOG, -mc));
                float p2 = exp2f(__builtin_fmaf(s[qt][nt][2], SCLOG, -mc));
                float p3 = exp2f(__builtin_fmaf(s[qt][nt][3], SCLOG, -mc));
                bf16x4 pk = { (bf16)p0, (bf16)p1, (bf16)p2, (bf16)p3 };
                *(bf16x4*)(prow + ((nt * 32 + lg * 8) ^ swz)) = pk;
            }
        }
        // ---- ctx += P V ; row-sums via ones-MFMA
        const char* vbase = (const char*)&Vb[cur][0][0];
        f32x4 sacc[2] = {};
#pragma unroll
        for (int ks = 0; ks < 2; ++ks) {
            bf16x8 pa[2];
#pragma unroll
            for (int qt = 0; qt < 2; ++qt) {
                pa[qt] = *(const bf16x8*)(prow0 + qt * 2048 + ((ks * 64 + lg * 16) ^ swz));
                sacc[qt] = __builtin_amdgcn_mfma_f32_16x16x32_bf16(pa[qt], ones, sacc[qt], 0, 0, 0);
            }
#pragma unroll
            for (int dt = 0; dt < 4; ++dt) {
                bf16x8 vf = *(const bf16x8*)(vbase + (dt * 16 + lr) * 128 + ((ks * 64 + lg * 16) ^ swz));
                cacc[0][dt] = __builtin_amdgcn_mfma_f32_16x16x32_bf16(pa[0], vf, cacc[0][dt], 0, 0, 0);
                cacc[1][dt] = __builtin_amdgcn_mfma_f32_16x16x32_bf16(pa[1], vf, cacc[1][dt], 0, 0, 0);
            }
        }
#pragma unroll
        for (int qt = 0; qt < 2; ++qt)
#pragma unroll
            for (int r = 0; r < 4; ++r) lrow[qt][r] += sacc[qt][r];
        __syncthreads();
        cur ^= 1;
    }
    const int b = bh >> 3, h = bh & 7;
#pragma unroll
    for (int qt = 0; qt < 2; ++qt) {
#pragma unroll
        for (int r = 0; r < 4; ++r) {
            float oolr = 1.0f / lrow[qt][r];
            int q = q0 + qt * 16 + lg * 4 + r;
#pragma unroll
            for (int dt = 0; dt < 4; ++dt)
                ctx[((size_t)(b * N + q)) * HD + h * 64 + dt * 16 + lr] =
                    (bf16)(cacc[qt][dt][r] * oolr);
        }
    }
}

// ---------------- output projection (split-K x2, atomic accumulate) --------
// 1 block/CU + 16-step serial K-chain was latency-bound; grid.y=2 halves the
// chain and doubles occupancy. out must be zeroed (hipMemsetAsync in launch).
__global__ __launch_bounds__(256) void out_gemm(
    const bf16* __restrict__ ctx, const bf16* __restrict__ Wot,
    float* __restrict__ out) {
    const int w = threadIdx.x >> 6, lane = threadIdx.x & 63;
    const int lr = lane & 15, lg = lane >> 4;
    const int m0 = blockIdx.x * 64 + w * 16;
    const int k0 = blockIdx.y * 8;            // 8 of 16 ks-steps
    f32x4 acc[4] = {};
#pragma unroll
    for (int ks = 0; ks < 8; ++ks) {
        bf16x8 af = *(const bf16x8*)(ctx + (size_t)(m0 + lr) * HD + (k0 + ks) * 32 + lg * 8);
#pragma unroll
        for (int nt = 0; nt < 4; ++nt) {
            bf16x8 wf = *(const bf16x8*)(Wot + (size_t)(nt * 16 + lr) * HD + (k0 + ks) * 32 + lg * 8);
            acc[nt] = __builtin_amdgcn_mfma_f32_16x16x32_bf16(af, wf, acc[nt], 0, 0, 0);
        }
    }
#pragma unroll
    for (int nt = 0; nt < 4; ++nt)
#pragma unroll
        for (int r = 0; r < 4; ++r)
            atomicAdd(&out[(size_t)(m0 + lg * 4 + r) * D + nt * 16 + lr], acc[nt][r]);
}

// ---------------- launcher ----------------
extern "C" void kernel_launch(void* const* d_in, const int* in_sizes, int n_in,
                              void* d_out, int out_size, void* d_ws, size_t ws_size,
                              hipStream_t stream) {
    (void)in_sizes; (void)n_in; (void)ws_size;
    const float* msg = (const float*)d_in[0];
    const float* Wq  = (const float*)d_in[1];
    const float* bq  = (const float*)d_in[2];
    const float* Wk  = (const float*)d_in[3];
    const float* bk  = (const float*)d_in[4];
    const float* Wv  = (const float*)d_in[5];
    const float* bv  = (const float*)d_in[6];
    const float* Wo  = (const float*)d_in[7];
    float* out = (float*)d_out;

    char* p = (char*)d_ws;
    bf16*  Abf  = (bf16*)p;  p += (size_t)M * IN * 2;      // 8 MB
    bf16*  Wt   = (bf16*)p;  p += (size_t)QKV * IN * 2;    // 768 KB
    float* bias = (float*)p; p += (size_t)QKV * 4;         // 6 KB
    bf16*  Wot  = (bf16*)p;  p += (size_t)D * HD * 2;      // 64 KB
    bf16*  Qb   = (bf16*)p;  p += (size_t)Bsz * H * N * D * 2;   // 16 MB
    bf16*  Kb   = (bf16*)p;  p += (size_t)Bsz * H * N * D * 2;   // 16 MB
    bf16*  Vtb  = (bf16*)p;  p += (size_t)Bsz * H * D * N * 2;   // 16 MB
    bf16*  Ctx  = (bf16*)p;  p += (size_t)M * HD * 2;            // 16 MB

    hipMemsetAsync(out, 0, (size_t)out_size * sizeof(float), stream);

    cvt_msg<<<(M * IN / 4) / 256, 256, 0, stream>>>(msg, Abf);
    pack_w<<<417, 256, 0, stream>>>(Wq, Wk, Wv, bq, bk, bv, Wo, Wt, bias, Wot);

    dim3 g1(M / 128, QKV / 128);     // 128 x 12
    qkv_gemm<<<g1, 256, 0, stream>>>(Abf, Wt, bias, Qb, Kb, Vtb);

    dim3 g2(Bsz * H, N / 256);       // 64 x 8 : 512 blocks, 2/CU
    attn_kernel<<<g2, 512, 0, stream>>>(Qb, Kb, Vtb, Ctx);

    dim3 g3(M / 64, 2);              // split-K x2: 512 blocks, 2/CU
    out_gemm<<<g3, 256, 0, stream>>>(Ctx, Wot, out);
}